// Round 12
// baseline (755.604 us; speedup 1.0000x reference)
//
#include <hip/hip_runtime.h>
#include <math.h>

#define BB 128
#define OUTROW 1259   // 2+1+256+1000

typedef float vf4 __attribute__((ext_vector_type(4)));

// ---------------- bf16 helpers ----------------
__device__ __forceinline__ ushort f2b(float x) {
    unsigned u = __float_as_uint(x);
    unsigned r = (u + 0x7FFFu + ((u >> 16) & 1u)) >> 16;   // RNE
    return (ushort)r;
}
__device__ __forceinline__ uint pack2(float lo, float hi) {
    return (uint)f2b(lo) | ((uint)f2b(hi) << 16);
}
__device__ __forceinline__ float dot2bf(uint a, uint b, float c) {
    float d;
    asm("v_dot2_f32_bf16 %0, %1, %2, %3" : "=v"(d) : "v"(a), "v"(b), "v"(c));
    return d;
}

// bf16 arena, pair-interleaved W2[kp][col] = uint{k=2kp, k=2kp+1} (ushort offsets)
#define OFF_W0   0u        // 256 kp * 256 c * 2 = 131072  (k padded 451->512)
#define OFF_RW   131072u   // 4 * 128 kp * 256 c * 2 = 262144
#define OFF_CW0  393216u   // 65536
#define OFF_CRW  458752u   // 65536
#define OFF_WF   524288u   // 128 kp * 272 c * 2 = 69632 (cols padded 259->272)
#define OFF_CW1  593920u   // 128 kp * 1024 c * 2 = 262144 (cols padded 1000->1024)
#define N_TOT    856064u

// ws float-offsets
#define WS_PIX    0u
#define WS_BFA    24576u     // 428032 floats of ushort arena
#define WS_INP2   452608u    // 128*256 uint
#define WS_AF     485376u    // 128*256 f32
#define WS_A2     518144u    // 128*128 uint
#define WS_BF     534528u
#define WS_B2     567296u
#define WS_WFO    583680u    // 128*272 f32
#define WS_LG     618496u    // 128*1024 f32
#define WS_BAR    749568u    // 256 uints

__device__ __forceinline__ void dirichlet_ab(float t, float& A, float& Bv) {
    float r = t - rintf(t);
    float s256 = sinpif(256.0f * r);
    Bv = s256 * (1.0f / 256.0f);
    if (fabsf(r) < 1e-6f) {
        A = 1.0f;
    } else {
        float sp = sinpif(r), cp = cospif(r);
        A = Bv * cp / sp;
    }
}

// blocks 0..383: NUDFT interp; blocks 384+: bf16 pair-convert.
__global__ __launch_bounds__(256) void interp_convert_kernel(
    const float* __restrict__ image, const float* __restrict__ loc,
    const float* __restrict__ scl, float* __restrict__ pix,
    const float* __restrict__ w0, const float* __restrict__ rw,
    const float* __restrict__ wf, const float* __restrict__ cw0,
    const float* __restrict__ crw, const float* __restrict__ cw1,
    ushort* __restrict__ bfa)
{
    __shared__ float U[256 * 16];
    __shared__ float V[16 * 260];
    __shared__ float T[16 * 260];

    int bid = blockIdx.x;
    int tid = threadIdx.x;

    if (bid >= 384) {
        unsigned g = (unsigned)(bid - 384) * 256u + (unsigned)tid;
        for (unsigned j = g; j < N_TOT; j += 512u * 256u) {
            if (j < 131072u) {                       // w0 (512k x 256c)
                unsigned kp = j >> 9, r = j & 511u, c = r >> 1, k = 2u*kp + (r & 1u);
                bfa[OFF_W0 + j] = (k < 451u) ? f2b(w0[k * 256u + c]) : (ushort)0;
            } else if (j < 393216u) {                // rw (1024k x 256c)
                unsigned jj = j - 131072u;
                unsigned kp = jj >> 9, r = jj & 511u, c = r >> 1, k = 2u*kp + (r & 1u);
                bfa[OFF_RW + jj] = f2b(rw[k * 256u + c]);
            } else if (j < 458752u) {                // cw0
                unsigned jj = j - 393216u;
                unsigned kp = jj >> 9, r = jj & 511u, c = r >> 1, k = 2u*kp + (r & 1u);
                bfa[OFF_CW0 + jj] = f2b(cw0[k * 256u + c]);
            } else if (j < 524288u) {                // crw
                unsigned jj = j - 458752u;
                unsigned kp = jj >> 9, r = jj & 511u, c = r >> 1, k = 2u*kp + (r & 1u);
                bfa[OFF_CRW + jj] = f2b(crw[k * 256u + c]);
            } else if (j < 593920u) {                // wf (256k x 272c pad)
                unsigned jj = j - 524288u;
                unsigned kp = jj / 544u, r = jj - kp * 544u, c = r >> 1, k = 2u*kp + (r & 1u);
                bfa[OFF_WF + jj] = (c < 259u) ? f2b(wf[k * 259u + c]) : (ushort)0;
            } else {                                 // cw1 (256k x 1024c pad)
                unsigned jj = j - 593920u;
                unsigned kp = jj / 2048u, r = jj - kp * 2048u, c = r >> 1, k = 2u*kp + (r & 1u);
                bfa[OFF_CW1 + jj] = (c < 1000u) ? f2b(cw1[k * 1000u + c]) : (ushort)0;
            }
        }
        return;
    }

    int b = bid / 3, c = bid % 3;
    float l0 = loc[2 * b], l1 = loc[2 * b + 1], sc = scl[b];

    {
        int p = tid;
        float tp = (float)p * (1.0f / 256.0f);
        #pragma unroll
        for (int iy = 0; iy < 8; ++iy) {
            float A, Bv;
            float y = ((float)iy * 0.125f - l0) * sc;
            dirichlet_ab(y - tp, A, Bv);
            int w = iy >> 1, o = iy & 1;
            U[p * 16 + w * 4 + o] = A;
            U[p * 16 + w * 4 + 2 + o] = Bv;
            float x = ((float)iy * 0.125f - l1) * sc;
            dirichlet_ab(x - tp, A, Bv);
            V[iy * 260 + p] = A;
            V[(8 + iy) * 260 + p] = Bv;
        }
    }
    __syncthreads();

    int wave = tid >> 6, lane = tid & 63;
    const float* img = image + (size_t)(b * 3 + c) * 65536 + lane * 4;

    float aA0[4] = {0, 0, 0, 0}, aA1[4] = {0, 0, 0, 0};
    float aB0[4] = {0, 0, 0, 0}, aB1[4] = {0, 0, 0, 0};
    #pragma unroll 4
    for (int p = 0; p < 256; ++p) {
        vf4 v = __builtin_nontemporal_load((const vf4*)(img + p * 256));
        const float4 u = *(const float4*)(&U[p * 16 + wave * 4]);
        aA0[0] += u.x * v[0]; aA0[1] += u.x * v[1]; aA0[2] += u.x * v[2]; aA0[3] += u.x * v[3];
        aA1[0] += u.y * v[0]; aA1[1] += u.y * v[1]; aA1[2] += u.y * v[2]; aA1[3] += u.y * v[3];
        aB0[0] += u.z * v[0]; aB0[1] += u.z * v[1]; aB0[2] += u.z * v[2]; aB0[3] += u.z * v[3];
        aB1[0] += u.w * v[0]; aB1[1] += u.w * v[1]; aB1[2] += u.w * v[2]; aB1[3] += u.w * v[3];
    }
    int iy0 = wave * 2;
    int q0 = lane * 4;
    #pragma unroll
    for (int j = 0; j < 4; ++j) {
        T[iy0 * 260 + q0 + j]       = aA0[j];
        T[(iy0 + 1) * 260 + q0 + j] = aA1[j];
        T[(8 + iy0) * 260 + q0 + j]     = aB0[j];
        T[(8 + iy0 + 1) * 260 + q0 + j] = aB1[j];
    }
    __syncthreads();

    int n = tid >> 2, sub = tid & 3;
    int iy = n >> 3, ix = n & 7;
    float s = 0.f;
    #pragma unroll 8
    for (int i = 0; i < 64; ++i) {
        int q = sub + 4 * i;
        s += T[iy * 260 + q] * V[ix * 260 + q] - T[(8 + iy) * 260 + q] * V[(8 + ix) * 260 + q];
    }
    s += __shfl_xor(s, 1);
    s += __shfl_xor(s, 2);
    if (sub == 0) pix[(b * 64 + n) * 3 + c] = s;
}

// ---- two-level grid barrier (128 blocks = 8 groups x 16), monotonic gens ----
__device__ __forceinline__ void gbar(uint* __restrict__ bar, int bb, uint gen) {
    __syncthreads();
    __threadfence();                       // release
    if (threadIdx.x == 0) {
        int g = bb >> 4;
        uint old = atomicAdd(&bar[g * 16], 1u);
        if (old == 16u * gen + 15u) atomicAdd(&bar[128], 1u);
        while (__hip_atomic_load(&bar[128], __ATOMIC_RELAXED, __HIP_MEMORY_SCOPE_AGENT)
               < 8u * (gen + 1u))
            __builtin_amdgcn_s_sleep(8);
    }
    __syncthreads();
    __threadfence();                       // acquire
}

// One 16x16 GEMM tile per block (cycled if ntiles>128). k = 2*KP.
// lane: c = lane&15 (col), s = lane>>4 (4-way k-split); wave = row-in-tile.
__device__ __forceinline__ void gemm_phase(
    const uint* __restrict__ A2, int KP,
    const uint* __restrict__ W2, int Cp, int tiles_c, int ntiles,
    const float* __restrict__ bias, int C_real,
    int mode,                               // 0 none, 1 relu, 2 tanh
    const float* __restrict__ resF,
    float* __restrict__ outF, int outStride,
    uint* __restrict__ out2,
    int bb, int tid)
{
    int lane = tid & 63, w = tid >> 6;
    int c = lane & 15, s = lane >> 4;
    int kq = KP >> 2;                       // kp per split
    for (int T = bb; T < ntiles; T += 128) {
        int rt = T / tiles_c, ct = T - rt * tiles_c;
        int row = rt * 16 + w, col = ct * 16 + c;
        const uint* Ar = A2 + row * KP + s * kq;
        const uint* Wp = W2 + (size_t)(s * kq) * Cp + col;
        float acc = 0.f;
        for (int ch = 0; ch < kq; ch += 8) {
            uint4 a0 = *(const uint4*)(Ar + ch);
            uint4 a1 = *(const uint4*)(Ar + ch + 4);
            const uint* wp = Wp + (size_t)ch * Cp;
            uint w0v = wp[0];
            uint w1v = wp[Cp];
            uint w2v = wp[2 * Cp];
            uint w3v = wp[3 * Cp];
            uint w4v = wp[4 * Cp];
            uint w5v = wp[5 * Cp];
            uint w6v = wp[6 * Cp];
            uint w7v = wp[7 * Cp];
            acc = dot2bf(w0v, a0.x, acc);
            acc = dot2bf(w1v, a0.y, acc);
            acc = dot2bf(w2v, a0.z, acc);
            acc = dot2bf(w3v, a0.w, acc);
            acc = dot2bf(w4v, a1.x, acc);
            acc = dot2bf(w5v, a1.y, acc);
            acc = dot2bf(w6v, a1.z, acc);
            acc = dot2bf(w7v, a1.w, acc);
        }
        acc += __shfl_xor(acc, 16);
        acc += __shfl_xor(acc, 32);
        float v = acc + ((col < C_real) ? bias[col] : 0.f);
        if (resF) v += resF[row * 256 + col];       // res layers are 256-wide
        if (mode == 1) v = fmaxf(v, 0.f);
        if (mode == 2) v = tanhf(v);
        float v2 = __shfl_xor(v, 1);
        if (s == 0 && col < C_real) outF[(size_t)row * outStride + col] = v;
        if (out2 && s == 0 && !(c & 1)) out2[row * (Cp >> 1) + (col >> 1)] = pack2(v, v2);
    }
}

// Cooperative-style MLP: 128 blocks x 1024 threads, grid barriers between layers.
__global__ __launch_bounds__(1024, 1) void mlp_coop(
    const float* __restrict__ loc, const float* __restrict__ scl,
    const float* __restrict__ hidden, const float* __restrict__ pix,
    const ushort* __restrict__ bfa, float* __restrict__ ws,
    const float* __restrict__ b0, const float* __restrict__ rb,
    const float* __restrict__ bfv, const float* __restrict__ cb0,
    const float* __restrict__ crb, const float* __restrict__ cb1,
    float* __restrict__ out)
{
    __shared__ float s_red[32];

    int bb = blockIdx.x, tid = threadIdx.x;
    uint*  bar   = (uint*)(ws + WS_BAR);
    uint*  inp2  = (uint*)(ws + WS_INP2);
    float* AF    = ws + WS_AF;   uint* A2v = (uint*)(ws + WS_A2);
    float* BF    = ws + WS_BF;   uint* B2v = (uint*)(ws + WS_B2);
    float* wfo   = ws + WS_WFO;
    float* lg    = ws + WS_LG;
    const uint* W0b  = (const uint*)(bfa + OFF_W0);
    const uint* RWb  = (const uint*)(bfa + OFF_RW);
    const uint* CW0b = (const uint*)(bfa + OFF_CW0);
    const uint* CRWb = (const uint*)(bfa + OFF_CRW);
    const uint* WFb  = (const uint*)(bfa + OFF_WF);
    const uint* CW1b = (const uint*)(bfa + OFF_CW1);
    float* orow = out + (size_t)bb * OUTROW;
    uint gen = 0;

    // ---- P0: build packed input row bb (512-padded) ----
    if (tid < 256) {
        int k0 = 2 * tid, k1 = k0 + 1;
        float lo, hi;
        lo = (k0 < 2) ? loc[2 * bb + k0] : (k0 == 2) ? scl[bb]
           : (k0 < 195) ? pix[bb * 192 + (k0 - 3)]
           : (k0 < 451) ? hidden[bb * 256 + (k0 - 195)] : 0.f;
        hi = (k1 < 2) ? loc[2 * bb + k1] : (k1 == 2) ? scl[bb]
           : (k1 < 195) ? pix[bb * 192 + (k1 - 3)]
           : (k1 < 451) ? hidden[bb * 256 + (k1 - 195)] : 0.f;
        inp2[bb * 256 + tid] = pack2(lo, hi);
    }
    gbar(bar, bb, gen++);

    // ---- P1: h0 = inp @ w0 + b0 ----
    gemm_phase(inp2, 256, W0b, 256, 16, 128, b0, 256, 0, nullptr, AF, 256, A2v, bb, tid);
    gbar(bar, bb, gen++);

    // ---- P2..P5: residual relu layers (layer stride = 32768 uints!) ----
    gemm_phase(A2v, 128, RWb,           256, 16, 128, rb,       256, 1, AF, BF, 256, B2v, bb, tid);
    gbar(bar, bb, gen++);
    gemm_phase(B2v, 128, RWb + 32768,   256, 16, 128, rb + 256, 256, 1, BF, AF, 256, A2v, bb, tid);
    gbar(bar, bb, gen++);
    gemm_phase(A2v, 128, RWb + 65536,   256, 16, 128, rb + 512, 256, 1, AF, BF, 256, B2v, bb, tid);
    gbar(bar, bb, gen++);
    gemm_phase(B2v, 128, RWb + 98304,   256, 16, 128, rb + 768, 256, 1, BF, AF, 256, A2v, bb, tid);
    gbar(bar, bb, gen++);

    // ---- P6: o = tanh(h @ wf + bf) ----
    gemm_phase(A2v, 128, WFb, 272, 17, 136, bfv, 259, 2, nullptr, wfo, 272, nullptr, bb, tid);
    gbar(bar, bb, gen++);

    // ---- P7: state update (row bb) ----
    if (tid < 256) {
        float nh = hidden[bb * 256 + tid] + wfo[bb * 272 + 3 + tid];
        orow[3 + tid] = nh;
        BF[bb * 256 + tid] = nh;
    } else if (tid < 259) {
        int i = tid - 256;
        float base = (i < 2) ? loc[2 * bb + i] : scl[bb];
        orow[i] = base + wfo[bb * 272 + i];
    } else if (tid >= 512 && tid < 640) {
        int kp = tid - 512;
        float lo = hidden[bb * 256 + 2 * kp]     + wfo[bb * 272 + 3 + 2 * kp];
        float hi = hidden[bb * 256 + 2 * kp + 1] + wfo[bb * 272 + 4 + 2 * kp];
        B2v[bb * 128 + kp] = pack2(lo, hi);
    }
    gbar(bar, bb, gen++);

    // ---- P8: c0 = relu(nh @ cw0 + cb0) ----
    gemm_phase(B2v, 128, CW0b, 256, 16, 128, cb0, 256, 1, nullptr, AF, 256, A2v, bb, tid);
    gbar(bar, bb, gen++);

    // ---- P9: c1 = relu(c0 @ crw + crb + c0) ----
    gemm_phase(A2v, 128, CRWb, 256, 16, 128, crb, 256, 1, AF, BF, 256, B2v, bb, tid);
    gbar(bar, bb, gen++);

    // ---- P10: logits = c1 @ cw1 + cb1 ----
    gemm_phase(B2v, 128, CW1b, 1024, 64, 512, cb1, 1000, 0, nullptr, lg, 1024, nullptr, bb, tid);
    gbar(bar, bb, gen++);

    // ---- P11: softmax row bb ----
    float lgv = (tid < 1000) ? lg[bb * 1024 + tid] : -1e30f;
    int lane = tid & 63, wid = tid >> 6;
    float m = lgv;
    #pragma unroll
    for (int off = 1; off < 64; off <<= 1) m = fmaxf(m, __shfl_xor(m, off));
    if (lane == 0) s_red[wid] = m;
    __syncthreads();
    m = s_red[0];
    #pragma unroll
    for (int w = 1; w < 16; ++w) m = fmaxf(m, s_red[w]);

    float e = (tid < 1000) ? expf(lgv - m) : 0.f;
    float lsum = e;
    #pragma unroll
    for (int off = 1; off < 64; off <<= 1) lsum += __shfl_xor(lsum, off);
    if (lane == 0) s_red[16 + wid] = lsum;
    __syncthreads();
    float total = 0.f;
    #pragma unroll
    for (int w = 0; w < 16; ++w) total += s_red[16 + w];

    if (tid < 1000) orow[259 + tid] = e / total;
}

extern "C" void kernel_launch(void* const* d_in, const int* in_sizes, int n_in,
                              void* d_out, int out_size, void* d_ws, size_t ws_size,
                              hipStream_t stream) {
    const float* image  = (const float*)d_in[0];
    const float* loc    = (const float*)d_in[1];
    const float* scl    = (const float*)d_in[2];
    const float* hidden = (const float*)d_in[3];
    const float* w0  = (const float*)d_in[4];
    const float* b0  = (const float*)d_in[5];
    const float* rw  = (const float*)d_in[6];
    const float* rb  = (const float*)d_in[7];
    const float* wf  = (const float*)d_in[8];
    const float* bf  = (const float*)d_in[9];
    const float* cw0 = (const float*)d_in[10];
    const float* cb0 = (const float*)d_in[11];
    const float* crw = (const float*)d_in[12];
    const float* crb = (const float*)d_in[13];
    const float* cw1 = (const float*)d_in[14];
    const float* cb1 = (const float*)d_in[15];

    float* ws   = (float*)d_ws;
    float* pix  = ws + WS_PIX;
    ushort* bfa = (ushort*)(ws + WS_BFA);

    hipMemsetAsync(ws + WS_BAR, 0, 1024, stream);
    hipLaunchKernelGGL(interp_convert_kernel, dim3(384 + 512), dim3(256), 0, stream,
                       image, loc, scl, pix, w0, rw, wf, cw0, crw, cw1, bfa);
    hipLaunchKernelGGL(mlp_coop, dim3(128), dim3(1024), 0, stream,
                       loc, scl, hidden, pix, bfa, ws,
                       b0, rb, bf, cb0, crb, cb1, (float*)d_out);
}

// Round 13
// 75.892 us; speedup vs baseline: 9.9563x; 9.9563x over previous
//
#include <hip/hip_runtime.h>
#include <math.h>

#define BB 128
#define OUTROW 1259   // 2+1+256+1000

typedef float vf4 __attribute__((ext_vector_type(4)));

// ---------------- bf16 helpers ----------------
__device__ __forceinline__ ushort f2b(float x) {
    unsigned u = __float_as_uint(x);
    unsigned r = (u + 0x7FFFu + ((u >> 16) & 1u)) >> 16;   // RNE
    return (ushort)r;
}
__device__ __forceinline__ uint pack2(float lo, float hi) {
    return (uint)f2b(lo) | ((uint)f2b(hi) << 16);
}
__device__ __forceinline__ float dot2bf(uint a, uint b, float c) {
    float d;
    asm("v_dot2_f32_bf16 %0, %1, %2, %3" : "=v"(d) : "v"(a), "v"(b), "v"(c));
    return d;
}

// bf16 arena: pair-interleaved layout W2[kp][col] (ushort offsets)
#define OFF_W0   0u        // 240 kp * 512          = 122880  (k padded 451->480)
#define OFF_RW   122880u   // 4 layers * 128kp*512  = 262144
#define OFF_CW0  385024u   // 128*512               = 65536
#define OFF_CRW  450560u   // 128*512               = 65536
#define OFF_WF   516096u   // 128 kp * 520 (260c)   = 66560   (col 259 zero-pad)
#define OFF_CW1  582656u   // 128 kp * 2048 (1024c) = 262144  (cols padded 1000->1024)
#define N_TOT    844800u

// ws float-offsets
#define WS_PIX   0u         // 24576
#define WS_BFA   24576u     // 422400 floats of ushort arena
#define WS_C1P   450048u    // 128*128 uint (packed c1)
#define WS_LG    466432u    // 128*1024 f32
// end: 597504 floats (~2.4 MB)

__device__ __forceinline__ void dirichlet_ab(float t, float& A, float& Bv) {
    float r = t - rintf(t);
    float s256 = sinpif(256.0f * r);
    Bv = s256 * (1.0f / 256.0f);
    if (fabsf(r) < 1e-6f) {
        A = 1.0f;
    } else {
        float sp = sinpif(r), cp = cospif(r);
        A = Bv * cp / sp;
    }
}

// blocks 0..383: NUDFT interp (one per (b,c)); blocks 384+: bf16 pair-convert.
__global__ __launch_bounds__(256) void interp_convert_kernel(
    const float* __restrict__ image, const float* __restrict__ loc,
    const float* __restrict__ scl, float* __restrict__ pix,
    const float* __restrict__ w0, const float* __restrict__ rw,
    const float* __restrict__ wf, const float* __restrict__ cw0,
    const float* __restrict__ crw, const float* __restrict__ cw1,
    ushort* __restrict__ bfa)
{
    __shared__ float U[256 * 16];
    __shared__ float V[16 * 260];
    __shared__ float T[16 * 260];

    int bid = blockIdx.x;
    int tid = threadIdx.x;

    if (bid >= 384) {
        unsigned g = (unsigned)(bid - 384) * 256u + (unsigned)tid;
        for (unsigned j = g; j < N_TOT; j += 512u * 256u) {
            if (j < 122880u) {                     // w0: C=256, 451 real rows
                unsigned kp = j >> 9, r = j & 511u, c = r >> 1, k = 2u*kp + (r & 1u);
                bfa[OFF_W0 + j] = (k < 451u) ? f2b(w0[k * 256u + c]) : (ushort)0;
            } else if (j < 385024u) {              // rw: 1024 rows x 256
                unsigned jj = j - 122880u;
                unsigned kp = jj >> 9, r = jj & 511u, c = r >> 1, k = 2u*kp + (r & 1u);
                bfa[OFF_RW + jj] = f2b(rw[k * 256u + c]);
            } else if (j < 450560u) {              // cw0
                unsigned jj = j - 385024u;
                unsigned kp = jj >> 9, r = jj & 511u, c = r >> 1, k = 2u*kp + (r & 1u);
                bfa[OFF_CW0 + jj] = f2b(cw0[k * 256u + c]);
            } else if (j < 516096u) {              // crw
                unsigned jj = j - 450560u;
                unsigned kp = jj >> 9, r = jj & 511u, c = r >> 1, k = 2u*kp + (r & 1u);
                bfa[OFF_CRW + jj] = f2b(crw[k * 256u + c]);
            } else if (j < 582656u) {              // wf: pitch 260 cols, 259 real
                unsigned jj = j - 516096u;
                unsigned kp = jj / 520u, r = jj - kp * 520u, c = r >> 1, k = 2u*kp + (r & 1u);
                bfa[OFF_WF + jj] = (c < 259u) ? f2b(wf[k * 259u + c]) : (ushort)0;
            } else {                               // cw1: 1024-padded cols
                unsigned jj = j - 582656u;
                unsigned kp = jj / 2048u, r = jj - kp * 2048u, c = r >> 1, k = 2u*kp + (r & 1u);
                bfa[OFF_CW1 + jj] = (c < 1000u) ? f2b(cw1[k * 1000u + c]) : (ushort)0;
            }
        }
        return;
    }

    int b = bid / 3, c = bid % 3;
    float l0 = loc[2 * b], l1 = loc[2 * b + 1], sc = scl[b];

    {
        int p = tid;
        float tp = (float)p * (1.0f / 256.0f);
        #pragma unroll
        for (int iy = 0; iy < 8; ++iy) {
            float A, Bv;
            float y = ((float)iy * 0.125f - l0) * sc;
            dirichlet_ab(y - tp, A, Bv);
            int w = iy >> 1, o = iy & 1;
            U[p * 16 + w * 4 + o] = A;
            U[p * 16 + w * 4 + 2 + o] = Bv;
            float x = ((float)iy * 0.125f - l1) * sc;
            dirichlet_ab(x - tp, A, Bv);
            V[iy * 260 + p] = A;
            V[(8 + iy) * 260 + p] = Bv;
        }
    }
    __syncthreads();

    int wave = tid >> 6, lane = tid & 63;
    const float* img = image + (size_t)(b * 3 + c) * 65536 + lane * 4;

    float aA0[4] = {0, 0, 0, 0}, aA1[4] = {0, 0, 0, 0};
    float aB0[4] = {0, 0, 0, 0}, aB1[4] = {0, 0, 0, 0};
    #pragma unroll 4
    for (int p = 0; p < 256; ++p) {
        vf4 v = __builtin_nontemporal_load((const vf4*)(img + p * 256));
        const float4 u = *(const float4*)(&U[p * 16 + wave * 4]);
        aA0[0] += u.x * v[0]; aA0[1] += u.x * v[1]; aA0[2] += u.x * v[2]; aA0[3] += u.x * v[3];
        aA1[0] += u.y * v[0]; aA1[1] += u.y * v[1]; aA1[2] += u.y * v[2]; aA1[3] += u.y * v[3];
        aB0[0] += u.z * v[0]; aB0[1] += u.z * v[1]; aB0[2] += u.z * v[2]; aB0[3] += u.z * v[3];
        aB1[0] += u.w * v[0]; aB1[1] += u.w * v[1]; aB1[2] += u.w * v[2]; aB1[3] += u.w * v[3];
    }
    int iy0 = wave * 2;
    int q0 = lane * 4;
    #pragma unroll
    for (int j = 0; j < 4; ++j) {
        T[iy0 * 260 + q0 + j]       = aA0[j];
        T[(iy0 + 1) * 260 + q0 + j] = aA1[j];
        T[(8 + iy0) * 260 + q0 + j]     = aB0[j];
        T[(8 + iy0 + 1) * 260 + q0 + j] = aB1[j];
    }
    __syncthreads();

    int n = tid >> 2, sub = tid & 3;
    int iy = n >> 3, ix = n & 7;
    float s = 0.f;
    #pragma unroll 8
    for (int i = 0; i < 64; ++i) {
        int q = sub + 4 * i;
        s += T[iy * 260 + q] * V[ix * 260 + q] - T[(8 + iy) * 260 + q] * V[(8 + ix) * 260 + q];
    }
    s += __shfl_xor(s, 1);
    s += __shfl_xor(s, 2);
    if (sub == 0) pix[(b * 64 + n) * 3 + c] = s;
}

// Per-row MLP chain through c1 (pair-packed bf16 + v_dot2_f32_bf16).
// jg = tid&63 owns cols 4jg..4jg+3; sub = tid>>6 owns k-pairs kp = sub+16t.
__global__ __launch_bounds__(1024, 1) void mlp_main(
    const float* __restrict__ loc, const float* __restrict__ scl,
    const float* __restrict__ hidden, const float* __restrict__ pix,
    const ushort* __restrict__ bfa,
    const float* __restrict__ b0, const float* __restrict__ rb,
    const float* __restrict__ bf, const float* __restrict__ cb0,
    const float* __restrict__ crb,
    uint* __restrict__ c1p, float* __restrict__ out)
{
    __shared__ float s_in[480];
    __shared__ float s_h[256];
    __shared__ float s_c[256];
    __shared__ float s_o[260];
    __shared__ float s_part[16 * 260];
    __shared__ uint  s_in2[240];
    __shared__ uint  s_hb2[128];
    __shared__ uint  s_cb2[128];
    __shared__ float s_b0[256], s_rb[1024], s_bf[260], s_cb0[256], s_crb[256];

    int b = blockIdx.x, tid = threadIdx.x;
    int jg = tid & 63, sub = tid >> 6;
    int j4 = jg * 4;
    float* orow = out + (size_t)b * OUTROW;

    // ---- stage inputs + biases ----
    if (tid < 2) s_in[tid] = loc[2 * b + tid];
    if (tid == 2) s_in[2] = scl[b];
    if (tid >= 256 && tid < 448) s_in[3 + (tid - 256)] = pix[b * 192 + (tid - 256)];
    if (tid >= 512 && tid < 768) s_in[195 + (tid - 512)] = hidden[b * 256 + (tid - 512)];
    if (tid >= 768 && tid < 797) s_in[451 + (tid - 768)] = 0.f;   // pad 451..479
    if (tid < 256) s_b0[tid] = b0[tid];
    s_rb[tid] = rb[tid];
    if (tid < 259) s_bf[tid] = bf[tid];
    if (tid >= 256 && tid < 512) s_cb0[tid - 256] = cb0[tid - 256];
    if (tid >= 512 && tid < 768) s_crb[tid - 512] = crb[tid - 512];
    __syncthreads();
    if (tid < 240) s_in2[tid] = pack2(s_in[2 * tid], s_in[2 * tid + 1]);
    __syncthreads();

    const ushort* w0b  = bfa + OFF_W0;
    const ushort* rwb  = bfa + OFF_RW;
    const ushort* cw0b = bfa + OFF_CW0;
    const ushort* crwb = bfa + OFF_CRW;
    const ushort* wfb  = bfa + OFF_WF;

    // ---- h0 = inp @ w0 + b0 (240 k-pairs, 15 per sub) ----
    {
        uint4 wv[15]; uint hv[15];
        #pragma unroll
        for (int t = 0; t < 15; ++t)
            wv[t] = *(const uint4*)(w0b + (size_t)(sub + 16 * t) * 512 + jg * 8);
        #pragma unroll
        for (int t = 0; t < 15; ++t) hv[t] = s_in2[sub + 16 * t];
        vf4 a = {0.f, 0.f, 0.f, 0.f};
        #pragma unroll
        for (int t = 0; t < 15; ++t) {
            a[0] = dot2bf(wv[t].x, hv[t], a[0]);
            a[1] = dot2bf(wv[t].y, hv[t], a[1]);
            a[2] = dot2bf(wv[t].z, hv[t], a[2]);
            a[3] = dot2bf(wv[t].w, hv[t], a[3]);
        }
        *(vf4*)(&s_part[sub * 256 + j4]) = a;
    }
    __syncthreads();
    if (tid < 256) {
        float v = s_b0[tid];
        #pragma unroll
        for (int s = 0; s < 16; ++s) v += s_part[s * 256 + tid];
        s_h[tid] = v;
        float v2 = __shfl_xor(v, 1);
        if (!(tid & 1)) s_hb2[tid >> 1] = pack2(v, v2);
    }
    __syncthreads();

    // ---- 4 residual layers: h = relu(h@rw + rb + h) ----
    #pragma unroll 1
    for (int L = 0; L < 4; ++L) {
        const ushort* W = rwb + (size_t)L * 65536;
        {
            uint4 wv[8]; uint hv[8];
            #pragma unroll
            for (int t = 0; t < 8; ++t)
                wv[t] = *(const uint4*)(W + (size_t)(sub + 16 * t) * 512 + jg * 8);
            #pragma unroll
            for (int t = 0; t < 8; ++t) hv[t] = s_hb2[sub + 16 * t];
            vf4 a = {0.f, 0.f, 0.f, 0.f};
            #pragma unroll
            for (int t = 0; t < 8; ++t) {
                a[0] = dot2bf(wv[t].x, hv[t], a[0]);
                a[1] = dot2bf(wv[t].y, hv[t], a[1]);
                a[2] = dot2bf(wv[t].z, hv[t], a[2]);
                a[3] = dot2bf(wv[t].w, hv[t], a[3]);
            }
            *(vf4*)(&s_part[sub * 256 + j4]) = a;
        }
        __syncthreads();
        if (tid < 256) {
            float v = s_rb[L * 256 + tid] + s_h[tid];
            #pragma unroll
            for (int s = 0; s < 16; ++s) v += s_part[s * 256 + tid];
            v = fmaxf(v, 0.f);
            s_h[tid] = v;
            float v2 = __shfl_xor(v, 1);
            if (!(tid & 1)) s_hb2[tid >> 1] = pack2(v, v2);
        }
        __syncthreads();
    }

    // ---- o = tanh(h @ wf + bf) (260-col padded) ----
    {
        uint4 wv[8]; uint hv[8];
        #pragma unroll
        for (int t = 0; t < 8; ++t)
            wv[t] = *(const uint4*)(wfb + (size_t)(sub + 16 * t) * 520 + jg * 8);
        #pragma unroll
        for (int t = 0; t < 8; ++t) hv[t] = s_hb2[sub + 16 * t];
        vf4 a = {0.f, 0.f, 0.f, 0.f};
        #pragma unroll
        for (int t = 0; t < 8; ++t) {
            a[0] = dot2bf(wv[t].x, hv[t], a[0]);
            a[1] = dot2bf(wv[t].y, hv[t], a[1]);
            a[2] = dot2bf(wv[t].z, hv[t], a[2]);
            a[3] = dot2bf(wv[t].w, hv[t], a[3]);
        }
        *(vf4*)(&s_part[sub * 260 + j4]) = a;
        if (jg < 4) {                                   // tail cols 256..259
            float e = 0.f;
            #pragma unroll
            for (int t = 0; t < 8; ++t) {
                uint w = *(const uint*)(wfb + (size_t)(sub + 16 * t) * 520 + 512 + jg * 2);
                e = dot2bf(w, hv[t], e);
            }
            s_part[sub * 260 + 256 + jg] = e;
        }
    }
    __syncthreads();
    if (tid < 259) {
        float v = s_bf[tid];
        #pragma unroll
        for (int s = 0; s < 16; ++s) v += s_part[s * 260 + tid];
        s_o[tid] = tanhf(v);
    }
    __syncthreads();

    // ---- state update + direct outputs ----
    if (tid < 256) {
        float nh = s_in[195 + tid] + s_o[3 + tid];
        orow[3 + tid] = nh;
        s_h[tid] = nh;
        float v2 = __shfl_xor(nh, 1);
        if (!(tid & 1)) s_hb2[tid >> 1] = pack2(nh, v2);
    }
    if (tid == 256) orow[0] = s_in[0] + s_o[0];
    if (tid == 257) orow[1] = s_in[1] + s_o[1];
    if (tid == 258) orow[2] = s_in[2] + s_o[2];
    __syncthreads();

    // ---- c0 = relu(nh @ cw0 + cb0) ----
    {
        uint4 wv[8]; uint hv[8];
        #pragma unroll
        for (int t = 0; t < 8; ++t)
            wv[t] = *(const uint4*)(cw0b + (size_t)(sub + 16 * t) * 512 + jg * 8);
        #pragma unroll
        for (int t = 0; t < 8; ++t) hv[t] = s_hb2[sub + 16 * t];
        vf4 a = {0.f, 0.f, 0.f, 0.f};
        #pragma unroll
        for (int t = 0; t < 8; ++t) {
            a[0] = dot2bf(wv[t].x, hv[t], a[0]);
            a[1] = dot2bf(wv[t].y, hv[t], a[1]);
            a[2] = dot2bf(wv[t].z, hv[t], a[2]);
            a[3] = dot2bf(wv[t].w, hv[t], a[3]);
        }
        *(vf4*)(&s_part[sub * 256 + j4]) = a;
    }
    __syncthreads();
    if (tid < 256) {
        float v = s_cb0[tid];
        #pragma unroll
        for (int s = 0; s < 16; ++s) v += s_part[s * 256 + tid];
        v = fmaxf(v, 0.f);
        s_c[tid] = v;
        float v2 = __shfl_xor(v, 1);
        if (!(tid & 1)) s_cb2[tid >> 1] = pack2(v, v2);
    }
    __syncthreads();

    // ---- c1 = relu(c0 @ crw + crb + c0) -> packed c1p ----
    {
        uint4 wv[8]; uint hv[8];
        #pragma unroll
        for (int t = 0; t < 8; ++t)
            wv[t] = *(const uint4*)(crwb + (size_t)(sub + 16 * t) * 512 + jg * 8);
        #pragma unroll
        for (int t = 0; t < 8; ++t) hv[t] = s_cb2[sub + 16 * t];
        vf4 a = {0.f, 0.f, 0.f, 0.f};
        #pragma unroll
        for (int t = 0; t < 8; ++t) {
            a[0] = dot2bf(wv[t].x, hv[t], a[0]);
            a[1] = dot2bf(wv[t].y, hv[t], a[1]);
            a[2] = dot2bf(wv[t].z, hv[t], a[2]);
            a[3] = dot2bf(wv[t].w, hv[t], a[3]);
        }
        *(vf4*)(&s_part[sub * 256 + j4]) = a;
    }
    __syncthreads();
    if (tid < 256) {
        float v = s_crb[tid] + s_c[tid];
        #pragma unroll
        for (int s = 0; s < 16; ++s) v += s_part[s * 256 + tid];
        v = fmaxf(v, 0.f);
        float v2 = __shfl_xor(v, 1);
        if (!(tid & 1)) c1p[b * 128 + (tid >> 1)] = pack2(v, v2);
    }
}

// logits = c1 @ cw1 + cb1, col-sliced: grid (128 rows, 8 slices of 128 cols).
// 1024 thr: cg = tid&31 owns 4 cols; sub = tid>>5 is a 32-way kp split.
__global__ __launch_bounds__(1024, 1) void logits_kernel(
    const uint* __restrict__ c1p, const ushort* __restrict__ bfa,
    const float* __restrict__ cb1, float* __restrict__ lg)
{
    __shared__ uint  s_c2[128];
    __shared__ float s_part[32 * 128];

    const uint* cw1b = (const uint*)(bfa + OFF_CW1);   // [kp][1024 cols]

    int b = blockIdx.x, s = blockIdx.y, tid = threadIdx.x;
    if (tid < 128) s_c2[tid] = c1p[b * 128 + tid];
    __syncthreads();

    int cg = tid & 31, sub = tid >> 5;
    int col0 = s * 128 + cg * 4;

    uint4 wv[4]; uint hv[4];
    #pragma unroll
    for (int t = 0; t < 4; ++t)
        wv[t] = *(const uint4*)(cw1b + (size_t)(sub + 32 * t) * 1024 + col0);
    #pragma unroll
    for (int t = 0; t < 4; ++t) hv[t] = s_c2[sub + 32 * t];
    vf4 a = {0.f, 0.f, 0.f, 0.f};
    #pragma unroll
    for (int t = 0; t < 4; ++t) {
        a[0] = dot2bf(wv[t].x, hv[t], a[0]);
        a[1] = dot2bf(wv[t].y, hv[t], a[1]);
        a[2] = dot2bf(wv[t].z, hv[t], a[2]);
        a[3] = dot2bf(wv[t].w, hv[t], a[3]);
    }
    *(vf4*)(&s_part[sub * 128 + cg * 4]) = a;
    __syncthreads();

    if (tid < 128) {
        int col = s * 128 + tid;
        if (col < 1000) {
            float v = cb1[col];
            #pragma unroll
            for (int ss = 0; ss < 32; ++ss) v += s_part[ss * 128 + tid];
            lg[(size_t)b * 1024 + col] = v;
        }
    }
}

// Per-row softmax over 1000 logits -> out[259..1258].
__global__ __launch_bounds__(1024) void softmax_kernel(
    const float* __restrict__ lg, float* __restrict__ out)
{
    __shared__ float s_red[32];
    int b = blockIdx.x, tid = threadIdx.x;
    float* orow = out + (size_t)b * OUTROW;

    float lgv = (tid < 1000) ? lg[(size_t)b * 1024 + tid] : -1e30f;

    int lane = tid & 63, wid = tid >> 6;
    float m = lgv;
    #pragma unroll
    for (int off = 1; off < 64; off <<= 1) m = fmaxf(m, __shfl_xor(m, off));
    if (lane == 0) s_red[wid] = m;
    __syncthreads();
    m = s_red[0];
    #pragma unroll
    for (int w = 1; w < 16; ++w) m = fmaxf(m, s_red[w]);

    float e = (tid < 1000) ? expf(lgv - m) : 0.f;
    float lsum = e;
    #pragma unroll
    for (int off = 1; off < 64; off <<= 1) lsum += __shfl_xor(lsum, off);
    if (lane == 0) s_red[16 + wid] = lsum;
    __syncthreads();
    float total = 0.f;
    #pragma unroll
    for (int w = 0; w < 16; ++w) total += s_red[16 + w];

    if (tid < 1000) orow[259 + tid] = e / total;
}

extern "C" void kernel_launch(void* const* d_in, const int* in_sizes, int n_in,
                              void* d_out, int out_size, void* d_ws, size_t ws_size,
                              hipStream_t stream) {
    const float* image  = (const float*)d_in[0];
    const float* loc    = (const float*)d_in[1];
    const float* scl    = (const float*)d_in[2];
    const float* hidden = (const float*)d_in[3];
    const float* w0  = (const float*)d_in[4];
    const float* b0  = (const float*)d_in[5];
    const float* rw  = (const float*)d_in[6];
    const float* rb  = (const float*)d_in[7];
    const float* wf  = (const float*)d_in[8];
    const float* bf  = (const float*)d_in[9];
    const float* cw0 = (const float*)d_in[10];
    const float* cb0 = (const float*)d_in[11];
    const float* crw = (const float*)d_in[12];
    const float* crb = (const float*)d_in[13];
    const float* cw1 = (const float*)d_in[14];
    const float* cb1 = (const float*)d_in[15];

    float* ws   = (float*)d_ws;
    float* pix  = ws + WS_PIX;
    ushort* bfa = (ushort*)(ws + WS_BFA);
    uint*  c1p  = (uint*)(ws + WS_C1P);
    float* lg   = ws + WS_LG;

    hipLaunchKernelGGL(interp_convert_kernel, dim3(384 + 512), dim3(256), 0, stream,
                       image, loc, scl, pix, w0, rw, wf, cw0, crw, cw1, bfa);
    hipLaunchKernelGGL(mlp_main, dim3(BB), dim3(1024), 0, stream,
                       loc, scl, hidden, pix, bfa,
                       b0, rb, bf, cb0, crb, c1p, (float*)d_out);
    hipLaunchKernelGGL(logits_kernel, dim3(BB, 8), dim3(1024), 0, stream,
                       c1p, bfa, cb1, lg);
    hipLaunchKernelGGL(softmax_kernel, dim3(BB), dim3(1024), 0, stream,
                       lg, (float*)d_out);
}

// Round 14
// 72.115 us; speedup vs baseline: 10.4777x; 1.0524x over previous
//
#include <hip/hip_runtime.h>
#include <math.h>

#define BB 128
#define OUTROW 1259   // 2+1+256+1000

typedef float vf4 __attribute__((ext_vector_type(4)));

// ---------------- bf16 helpers ----------------
__device__ __forceinline__ ushort f2b(float x) {
    unsigned u = __float_as_uint(x);
    unsigned r = (u + 0x7FFFu + ((u >> 16) & 1u)) >> 16;   // RNE
    return (ushort)r;
}
__device__ __forceinline__ uint pack2(float lo, float hi) {
    return (uint)f2b(lo) | ((uint)f2b(hi) << 16);
}
// D = a.bf16[0]*b.bf16[0] + a.bf16[1]*b.bf16[1] + c   (f32 accumulate)
__device__ __forceinline__ float dot2bf(uint a, uint b, float c) {
    float d;
    asm("v_dot2_f32_bf16 %0, %1, %2, %3" : "=v"(d) : "v"(a), "v"(b), "v"(c));
    return d;
}

// bf16 arena: pair-interleaved layout W2[k/2][col][2] (ushort offsets)
#define OFF_W0   0u        // 240 kp * 512          = 122880  (k padded 451->480)
#define OFF_RW   122880u   // 4 layers * 128kp*512  = 262144
#define OFF_CW0  385024u   // 128*512               = 65536
#define OFF_CRW  450560u   // 128*512               = 65536
#define OFF_WF   516096u   // 128 kp * 520 (260c)   = 66560   (col 259 zero-pad)
#define OFF_CW1  582656u   // 128 kp * 2000 (1000c) = 256000
#define N_TOT    838656u   // ushorts = 419328 uints

__device__ __forceinline__ void dirichlet_ab(float t, float& A, float& Bv) {
    float r = t - rintf(t);
    float s256 = sinpif(256.0f * r);
    Bv = s256 * (1.0f / 256.0f);
    if (fabsf(r) < 1e-6f) {
        A = 1.0f;
    } else {
        float sp = sinpif(r), cp = cospif(r);
        A = Bv * cp / sp;
    }
}

// blocks 0..383: NUDFT interp (one per (b,c)); blocks 384+: bf16 pair-convert.
__global__ __launch_bounds__(256) void interp_convert_kernel(
    const float* __restrict__ image, const float* __restrict__ loc,
    const float* __restrict__ scl, float* __restrict__ pix,
    const float* __restrict__ w0, const float* __restrict__ rw,
    const float* __restrict__ wf, const float* __restrict__ cw0,
    const float* __restrict__ crw, const float* __restrict__ cw1,
    ushort* __restrict__ bfa)
{
    __shared__ float U[256 * 16];
    __shared__ float V[16 * 260];
    __shared__ float T[16 * 260];

    int bid = blockIdx.x;
    int tid = threadIdx.x;

    if (bid >= 384) {
        unsigned g = (unsigned)(bid - 384) * 256u + (unsigned)tid;
        for (unsigned j = g; j < N_TOT; j += 512u * 256u) {
            if (j < 122880u) {                     // w0: C=256, 451 real rows
                unsigned kp = j >> 9, r = j & 511u, c = r >> 1, k = 2u*kp + (r & 1u);
                bfa[OFF_W0 + j] = (k < 451u) ? f2b(w0[k * 256u + c]) : (ushort)0;
            } else if (j < 385024u) {              // rw
                unsigned jj = j - 122880u;
                unsigned kp = jj >> 9, r = jj & 511u, c = r >> 1, k = 2u*kp + (r & 1u);
                bfa[OFF_RW + jj] = f2b(rw[k * 256u + c]);
            } else if (j < 450560u) {              // cw0
                unsigned jj = j - 385024u;
                unsigned kp = jj >> 9, r = jj & 511u, c = r >> 1, k = 2u*kp + (r & 1u);
                bfa[OFF_CW0 + jj] = f2b(cw0[k * 256u + c]);
            } else if (j < 516096u) {              // crw
                unsigned jj = j - 450560u;
                unsigned kp = jj >> 9, r = jj & 511u, c = r >> 1, k = 2u*kp + (r & 1u);
                bfa[OFF_CRW + jj] = f2b(crw[k * 256u + c]);
            } else if (j < 582656u) {              // wf: pitch 260 cols, 259 real
                unsigned jj = j - 516096u;
                unsigned kp = jj / 520u, r = jj - kp * 520u, c = r >> 1, k = 2u*kp + (r & 1u);
                bfa[OFF_WF + jj] = (c < 259u) ? f2b(wf[k * 259u + c]) : (ushort)0;
            } else {                               // cw1: 1000 cols
                unsigned jj = j - 582656u;
                unsigned kp = jj / 2000u, r = jj - kp * 2000u, c = r >> 1, k = 2u*kp + (r & 1u);
                bfa[OFF_CW1 + jj] = f2b(cw1[k * 1000u + c]);
            }
        }
        return;
    }

    int b = bid / 3, c = bid % 3;
    float l0 = loc[2 * b], l1 = loc[2 * b + 1], sc = scl[b];

    {
        int p = tid;
        float tp = (float)p * (1.0f / 256.0f);
        #pragma unroll
        for (int iy = 0; iy < 8; ++iy) {
            float A, Bv;
            float y = ((float)iy * 0.125f - l0) * sc;
            dirichlet_ab(y - tp, A, Bv);
            int w = iy >> 1, o = iy & 1;
            U[p * 16 + w * 4 + o] = A;
            U[p * 16 + w * 4 + 2 + o] = Bv;
            float x = ((float)iy * 0.125f - l1) * sc;
            dirichlet_ab(x - tp, A, Bv);
            V[iy * 260 + p] = A;
            V[(8 + iy) * 260 + p] = Bv;
        }
    }
    __syncthreads();

    int wave = tid >> 6, lane = tid & 63;
    const float* img = image + (size_t)(b * 3 + c) * 65536 + lane * 4;

    float aA0[4] = {0, 0, 0, 0}, aA1[4] = {0, 0, 0, 0};
    float aB0[4] = {0, 0, 0, 0}, aB1[4] = {0, 0, 0, 0};
    #pragma unroll 4
    for (int p = 0; p < 256; ++p) {
        vf4 v = __builtin_nontemporal_load((const vf4*)(img + p * 256));
        const float4 u = *(const float4*)(&U[p * 16 + wave * 4]);
        aA0[0] += u.x * v[0]; aA0[1] += u.x * v[1]; aA0[2] += u.x * v[2]; aA0[3] += u.x * v[3];
        aA1[0] += u.y * v[0]; aA1[1] += u.y * v[1]; aA1[2] += u.y * v[2]; aA1[3] += u.y * v[3];
        aB0[0] += u.z * v[0]; aB0[1] += u.z * v[1]; aB0[2] += u.z * v[2]; aB0[3] += u.z * v[3];
        aB1[0] += u.w * v[0]; aB1[1] += u.w * v[1]; aB1[2] += u.w * v[2]; aB1[3] += u.w * v[3];
    }
    int iy0 = wave * 2;
    int q0 = lane * 4;
    #pragma unroll
    for (int j = 0; j < 4; ++j) {
        T[iy0 * 260 + q0 + j]       = aA0[j];
        T[(iy0 + 1) * 260 + q0 + j] = aA1[j];
        T[(8 + iy0) * 260 + q0 + j]     = aB0[j];
        T[(8 + iy0 + 1) * 260 + q0 + j] = aB1[j];
    }
    __syncthreads();

    int n = tid >> 2, sub = tid & 3;
    int iy = n >> 3, ix = n & 7;
    float s = 0.f;
    #pragma unroll 8
    for (int i = 0; i < 64; ++i) {
        int q = sub + 4 * i;
        s += T[iy * 260 + q] * V[ix * 260 + q] - T[(8 + iy) * 260 + q] * V[(8 + ix) * 260 + q];
    }
    s += __shfl_xor(s, 1);
    s += __shfl_xor(s, 2);
    if (sub == 0) pix[(b * 64 + n) * 3 + c] = s;
}

// Monolithic per-row MLP (blocks 0..127) + L2-warmer blocks (128..255).
// Warmers: slice = (bid-128)>>3 so each XCD's 16 warmers (round-robin bid%8)
// cover the whole arena in that XCD's L2. Read-only, fixed trip count.
__global__ __launch_bounds__(1024, 1) void mlp_fused(
    const float* __restrict__ loc, const float* __restrict__ scl,
    const float* __restrict__ hidden, const float* __restrict__ pix,
    const ushort* __restrict__ bfa,
    const float* __restrict__ b0, const float* __restrict__ rb,
    const float* __restrict__ bf, const float* __restrict__ cb0,
    const float* __restrict__ crb, const float* __restrict__ cb1,
    float* __restrict__ out, float* __restrict__ sink)
{
    __shared__ float s_in[480];
    __shared__ float s_h[256];
    __shared__ float s_c[256];
    __shared__ float s_o[260];
    __shared__ float s_part[16 * 260];
    __shared__ float s_lg[1024];
    __shared__ uint  s_in2[240];
    __shared__ uint  s_hb2[128];
    __shared__ uint  s_cb2[128];
    __shared__ float s_b0[256], s_rb[1024], s_bf[260], s_cb0[256], s_crb[256], s_cb1[1000];
    __shared__ float s_red[32];

    int bid = blockIdx.x, tid = threadIdx.x;

    if (bid >= BB) {
        // ---------- L2 warmer ----------
        const uint* A = (const uint*)bfa;            // 419328 uints
        int w = bid - BB;
        int slice = w >> 3;                          // 0..15
        unsigned SL = 26208u;                        // 419328/16
        unsigned lo = slice * SL, hi = lo + SL;
        float acc = 0.f;
        for (int it = 0; it < 16; ++it) {
            for (unsigned i = lo + tid * 4u; i + 3u < hi; i += 4096u) {
                uint4 v = *(const uint4*)(A + i);
                acc += (float)(v.x ^ v.y ^ v.z ^ v.w);
            }
        }
        if (acc == 1.0e30f) sink[0] = acc;           // never true; keeps loads live
        return;
    }

    int b = bid;
    int jg = tid & 63, sub = tid >> 6;
    int j4 = jg * 4;
    float* orow = out + (size_t)b * OUTROW;

    // ---- stage inputs + biases ----
    if (tid < 2) s_in[tid] = loc[2 * b + tid];
    if (tid == 2) s_in[2] = scl[b];
    if (tid >= 256 && tid < 448) s_in[3 + (tid - 256)] = pix[b * 192 + (tid - 256)];
    if (tid >= 512 && tid < 768) s_in[195 + (tid - 512)] = hidden[b * 256 + (tid - 512)];
    if (tid >= 768 && tid < 797) s_in[451 + (tid - 768)] = 0.f;   // pad 451..479
    if (tid < 256) s_b0[tid] = b0[tid];
    s_rb[tid] = rb[tid];
    if (tid < 259) s_bf[tid] = bf[tid];
    if (tid >= 256 && tid < 512) s_cb0[tid - 256] = cb0[tid - 256];
    if (tid >= 512 && tid < 768) s_crb[tid - 512] = crb[tid - 512];
    if (tid < 1000) s_cb1[tid] = cb1[tid];
    __syncthreads();
    if (tid < 240) s_in2[tid] = pack2(s_in[2 * tid], s_in[2 * tid + 1]);
    __syncthreads();

    const ushort* w0b  = bfa + OFF_W0;
    const ushort* rwb  = bfa + OFF_RW;
    const ushort* cw0b = bfa + OFF_CW0;
    const ushort* crwb = bfa + OFF_CRW;
    const ushort* wfb  = bfa + OFF_WF;
    const ushort* cw1b = bfa + OFF_CW1;

    // ---- h0 = inp @ w0 + b0 (240 k-pairs, 15 per sub) ----
    {
        uint4 wv[15]; uint hv[15];
        #pragma unroll
        for (int t = 0; t < 15; ++t)
            wv[t] = *(const uint4*)(w0b + (size_t)(sub + 16 * t) * 512 + jg * 8);
        #pragma unroll
        for (int t = 0; t < 15; ++t) hv[t] = s_in2[sub + 16 * t];
        vf4 a = {0.f, 0.f, 0.f, 0.f};
        #pragma unroll
        for (int t = 0; t < 15; ++t) {
            a[0] = dot2bf(wv[t].x, hv[t], a[0]);
            a[1] = dot2bf(wv[t].y, hv[t], a[1]);
            a[2] = dot2bf(wv[t].z, hv[t], a[2]);
            a[3] = dot2bf(wv[t].w, hv[t], a[3]);
        }
        *(vf4*)(&s_part[sub * 256 + j4]) = a;
    }
    __syncthreads();
    if (tid < 256) {
        float v = s_b0[tid];
        #pragma unroll
        for (int s = 0; s < 16; ++s) v += s_part[s * 256 + tid];
        s_h[tid] = v;
        float v2 = __shfl_xor(v, 1);
        if (!(tid & 1)) s_hb2[tid >> 1] = pack2(v, v2);
    }
    __syncthreads();

    // ---- 4 residual layers: h = relu(h@rw + rb + h) ----
    #pragma unroll 1
    for (int L = 0; L < 4; ++L) {
        const ushort* W = rwb + (size_t)L * 65536;
        {
            uint4 wv[8]; uint hv[8];
            #pragma unroll
            for (int t = 0; t < 8; ++t)
                wv[t] = *(const uint4*)(W + (size_t)(sub + 16 * t) * 512 + jg * 8);
            #pragma unroll
            for (int t = 0; t < 8; ++t) hv[t] = s_hb2[sub + 16 * t];
            vf4 a = {0.f, 0.f, 0.f, 0.f};
            #pragma unroll
            for (int t = 0; t < 8; ++t) {
                a[0] = dot2bf(wv[t].x, hv[t], a[0]);
                a[1] = dot2bf(wv[t].y, hv[t], a[1]);
                a[2] = dot2bf(wv[t].z, hv[t], a[2]);
                a[3] = dot2bf(wv[t].w, hv[t], a[3]);
            }
            *(vf4*)(&s_part[sub * 256 + j4]) = a;
        }
        __syncthreads();
        if (tid < 256) {
            float v = s_rb[L * 256 + tid] + s_h[tid];
            #pragma unroll
            for (int s = 0; s < 16; ++s) v += s_part[s * 256 + tid];
            v = fmaxf(v, 0.f);
            s_h[tid] = v;
            float v2 = __shfl_xor(v, 1);
            if (!(tid & 1)) s_hb2[tid >> 1] = pack2(v, v2);
        }
        __syncthreads();
    }

    // ---- o = tanh(h @ wf + bf) (260-col padded) ----
    {
        uint4 wv[8]; uint hv[8];
        #pragma unroll
        for (int t = 0; t < 8; ++t)
            wv[t] = *(const uint4*)(wfb + (size_t)(sub + 16 * t) * 520 + jg * 8);
        #pragma unroll
        for (int t = 0; t < 8; ++t) hv[t] = s_hb2[sub + 16 * t];
        vf4 a = {0.f, 0.f, 0.f, 0.f};
        #pragma unroll
        for (int t = 0; t < 8; ++t) {
            a[0] = dot2bf(wv[t].x, hv[t], a[0]);
            a[1] = dot2bf(wv[t].y, hv[t], a[1]);
            a[2] = dot2bf(wv[t].z, hv[t], a[2]);
            a[3] = dot2bf(wv[t].w, hv[t], a[3]);
        }
        *(vf4*)(&s_part[sub * 260 + j4]) = a;
        if (jg < 4) {                                   // tail cols 256..259
            float e = 0.f;
            #pragma unroll
            for (int t = 0; t < 8; ++t) {
                uint w = *(const uint*)(wfb + (size_t)(sub + 16 * t) * 520 + 512 + jg * 2);
                e = dot2bf(w, hv[t], e);
            }
            s_part[sub * 260 + 256 + jg] = e;
        }
    }
    __syncthreads();
    if (tid < 259) {
        float v = s_bf[tid];
        #pragma unroll
        for (int s = 0; s < 16; ++s) v += s_part[s * 260 + tid];
        s_o[tid] = tanhf(v);
    }
    __syncthreads();

    // ---- state update + direct outputs ----
    if (tid < 256) {
        float nh = s_in[195 + tid] + s_o[3 + tid];
        orow[3 + tid] = nh;
        s_h[tid] = nh;
        float v2 = __shfl_xor(nh, 1);
        if (!(tid & 1)) s_hb2[tid >> 1] = pack2(nh, v2);
    }
    if (tid == 256) orow[0] = s_in[0] + s_o[0];
    if (tid == 257) orow[1] = s_in[1] + s_o[1];
    if (tid == 258) orow[2] = s_in[2] + s_o[2];
    __syncthreads();

    // ---- c0 = relu(nh @ cw0 + cb0) ----
    {
        uint4 wv[8]; uint hv[8];
        #pragma unroll
        for (int t = 0; t < 8; ++t)
            wv[t] = *(const uint4*)(cw0b + (size_t)(sub + 16 * t) * 512 + jg * 8);
        #pragma unroll
        for (int t = 0; t < 8; ++t) hv[t] = s_hb2[sub + 16 * t];
        vf4 a = {0.f, 0.f, 0.f, 0.f};
        #pragma unroll
        for (int t = 0; t < 8; ++t) {
            a[0] = dot2bf(wv[t].x, hv[t], a[0]);
            a[1] = dot2bf(wv[t].y, hv[t], a[1]);
            a[2] = dot2bf(wv[t].z, hv[t], a[2]);
            a[3] = dot2bf(wv[t].w, hv[t], a[3]);
        }
        *(vf4*)(&s_part[sub * 256 + j4]) = a;
    }
    __syncthreads();
    if (tid < 256) {
        float v = s_cb0[tid];
        #pragma unroll
        for (int s = 0; s < 16; ++s) v += s_part[s * 256 + tid];
        v = fmaxf(v, 0.f);
        s_c[tid] = v;
        float v2 = __shfl_xor(v, 1);
        if (!(tid & 1)) s_cb2[tid >> 1] = pack2(v, v2);
    }
    __syncthreads();

    // ---- c1 = relu(c0 @ crw + crb + c0) ----
    {
        uint4 wv[8]; uint hv[8];
        #pragma unroll
        for (int t = 0; t < 8; ++t)
            wv[t] = *(const uint4*)(crwb + (size_t)(sub + 16 * t) * 512 + jg * 8);
        #pragma unroll
        for (int t = 0; t < 8; ++t) hv[t] = s_cb2[sub + 16 * t];
        vf4 a = {0.f, 0.f, 0.f, 0.f};
        #pragma unroll
        for (int t = 0; t < 8; ++t) {
            a[0] = dot2bf(wv[t].x, hv[t], a[0]);
            a[1] = dot2bf(wv[t].y, hv[t], a[1]);
            a[2] = dot2bf(wv[t].z, hv[t], a[2]);
            a[3] = dot2bf(wv[t].w, hv[t], a[3]);
        }
        *(vf4*)(&s_part[sub * 256 + j4]) = a;
    }
    __syncthreads();
    if (tid < 256) {
        float v = s_crb[tid] + s_c[tid];
        #pragma unroll
        for (int s = 0; s < 16; ++s) v += s_part[s * 256 + tid];
        v = fmaxf(v, 0.f);
        float v2 = __shfl_xor(v, 1);
        if (!(tid & 1)) s_cb2[tid >> 1] = pack2(v, v2);
    }
    __syncthreads();

    // ---- logits pass 1: cols 0..511 (8-way kp split) ----
    int jg8 = tid & 127, sub8 = tid >> 7;
    int c4 = jg8 * 4;
    {
        uint4 wv[16]; uint hv[16];
        #pragma unroll
        for (int t = 0; t < 16; ++t)
            wv[t] = *(const uint4*)(cw1b + (size_t)(sub8 + 8 * t) * 2000 + c4 * 2);
        #pragma unroll
        for (int t = 0; t < 16; ++t) hv[t] = s_cb2[sub8 + 8 * t];
        vf4 a = {0.f, 0.f, 0.f, 0.f};
        #pragma unroll
        for (int t = 0; t < 16; ++t) {
            a[0] = dot2bf(wv[t].x, hv[t], a[0]);
            a[1] = dot2bf(wv[t].y, hv[t], a[1]);
            a[2] = dot2bf(wv[t].z, hv[t], a[2]);
            a[3] = dot2bf(wv[t].w, hv[t], a[3]);
        }
        *(vf4*)(&s_part[sub8 * 512 + c4]) = a;
    }
    __syncthreads();
    if (tid < 512) {
        float v = s_cb1[tid];
        #pragma unroll
        for (int s = 0; s < 8; ++s) v += s_part[s * 512 + tid];
        s_lg[tid] = v;
    }
    __syncthreads();

    // ---- logits pass 2: cols 512..999 ----
    {
        vf4 a = {0.f, 0.f, 0.f, 0.f};
        if (jg8 < 122) {
            uint4 wv[16]; uint hv[16];
            #pragma unroll
            for (int t = 0; t < 16; ++t)
                wv[t] = *(const uint4*)(cw1b + (size_t)(sub8 + 8 * t) * 2000 + (512 + c4) * 2);
            #pragma unroll
            for (int t = 0; t < 16; ++t) hv[t] = s_cb2[sub8 + 8 * t];
            #pragma unroll
            for (int t = 0; t < 16; ++t) {
                a[0] = dot2bf(wv[t].x, hv[t], a[0]);
                a[1] = dot2bf(wv[t].y, hv[t], a[1]);
                a[2] = dot2bf(wv[t].z, hv[t], a[2]);
                a[3] = dot2bf(wv[t].w, hv[t], a[3]);
            }
        }
        *(vf4*)(&s_part[sub8 * 512 + c4]) = a;
    }
    __syncthreads();
    if (tid < 488) {
        float v = s_cb1[512 + tid];
        #pragma unroll
        for (int s = 0; s < 8; ++s) v += s_part[s * 512 + tid];
        s_lg[512 + tid] = v;
    }
    __syncthreads();

    // ---- softmax over 1000 ----
    float lgv = (tid < 1000) ? s_lg[tid] : -1e30f;
    int lane = tid & 63, wid = tid >> 6;
    float m = lgv;
    #pragma unroll
    for (int off = 1; off < 64; off <<= 1) m = fmaxf(m, __shfl_xor(m, off));
    if (lane == 0) s_red[wid] = m;
    __syncthreads();
    m = s_red[0];
    #pragma unroll
    for (int w = 1; w < 16; ++w) m = fmaxf(m, s_red[w]);

    float e = (tid < 1000) ? expf(lgv - m) : 0.f;
    float lsum = e;
    #pragma unroll
    for (int off = 1; off < 64; off <<= 1) lsum += __shfl_xor(lsum, off);
    if (lane == 0) s_red[16 + wid] = lsum;
    __syncthreads();
    float total = 0.f;
    #pragma unroll
    for (int w = 0; w < 16; ++w) total += s_red[16 + w];

    if (tid < 1000) orow[259 + tid] = e / total;
}

extern "C" void kernel_launch(void* const* d_in, const int* in_sizes, int n_in,
                              void* d_out, int out_size, void* d_ws, size_t ws_size,
                              hipStream_t stream) {
    const float* image  = (const float*)d_in[0];
    const float* loc    = (const float*)d_in[1];
    const float* scl    = (const float*)d_in[2];
    const float* hidden = (const float*)d_in[3];
    const float* w0  = (const float*)d_in[4];
    const float* b0  = (const float*)d_in[5];
    const float* rw  = (const float*)d_in[6];
    const float* rb  = (const float*)d_in[7];
    const float* wf  = (const float*)d_in[8];
    const float* bf  = (const float*)d_in[9];
    const float* cw0 = (const float*)d_in[10];
    const float* cb0 = (const float*)d_in[11];
    const float* crw = (const float*)d_in[12];
    const float* crb = (const float*)d_in[13];
    const float* cw1 = (const float*)d_in[14];
    const float* cb1 = (const float*)d_in[15];

    float* ws   = (float*)d_ws;
    float* pix  = ws;                          // 24576 floats
    ushort* bfa = (ushort*)(ws + 24576);       // 838656 ushorts (~1.68 MB)
    float* sink = ws + 24576 + 419328 + 8;

    hipLaunchKernelGGL(interp_convert_kernel, dim3(384 + 512), dim3(256), 0, stream,
                       image, loc, scl, pix, w0, rw, wf, cw0, crw, cw1, bfa);
    hipLaunchKernelGGL(mlp_fused, dim3(256), dim3(1024), 0, stream,
                       loc, scl, hidden, pix, bfa,
                       b0, rb, bf, cb0, crb, cb1, (float*)d_out, sink);
}